// Round 6
// baseline (314.764 us; speedup 1.0000x reference)
//
#include <hip/hip_runtime.h>
#include <hip/hip_bf16.h>

// Complex ConvLSTM cell. Inputs f32, output f32.
//   Zp: halo-padded packed activations, [b][y' 0..65][x' 0..65][cin 0..255] bf16
//   Wp[n][tap][cin]: n = part*64+ch, parts {yr_i,yi_i,yr_o,yi_o,yr_c,yi_c}
//   conv_fused R6: R5 structure + conflict-free LDS layouts.
//     A/B use paired-row 8-slot swizzle: slot=(row>>1)*8+((2*kg+(row&7))&7)
//     -> frag reads hit 8 distinct bank-groups per 16-lane quad (2 lanes each,
//     free) vs R5's 4-slot XOR (4-way intra-quad). Staging pre-swizzles the
//     global source (rule: both-sides-or-neither with global_load_lds).
//     Epilogue exchange: stride 68 shorts, 2 c-half x 2 px-row rounds ->
//     writes hit all 32 banks 2 lanes each (was 8-way at stride 64).
//   prep R6: pack_z is LDS-free (old tile stores were 16-way conflicts,
//     prep ~130us vs 17us floor). Reads 8xfloat2 (64B/8-lane coalesced),
//     writes 2xshort8 (128B per pixel). Bitwise-identical Zp.

typedef __attribute__((ext_vector_type(8))) short short8;
typedef __attribute__((ext_vector_type(4))) float floatx4;
typedef __attribute__((ext_vector_type(4))) float float4v;
typedef __attribute__((ext_vector_type(2))) float float2v;

#define HSIZE  8388608

__device__ __forceinline__ short f2bf(float f) {
  __hip_bfloat16 h = __float2bfloat16(f);
  return *reinterpret_cast<short*>(&h);
}

__device__ __forceinline__ float bf2f(short s) {
  unsigned u = ((unsigned)(unsigned short)s) << 16;
  return __uint_as_float(u);
}

__device__ __forceinline__ void gload16(const short* g, void* lds) {
  __builtin_amdgcn_global_load_lds(
      (__attribute__((address_space(1))) void*)(g),
      (__attribute__((address_space(3))) void*)(lds), 16, 0, 0);
}

// ---------------------------------------------------------------- fused prep
// blocks [0,520): halo zero; [520,4616): pack_z (LDS-free); [4616,8072): pack_w.
__global__ __launch_bounds__(256) void prep_kernel(
    const float* __restrict__ xs, const float* __restrict__ hs,
    short* __restrict__ Zp,
    const float* __restrict__ Wr_i, const float* __restrict__ Wi_i,
    const float* __restrict__ Wr_o, const float* __restrict__ Wi_o,
    const float* __restrict__ Wr_c, const float* __restrict__ Wi_c,
    const float* __restrict__ br_i, const float* __restrict__ bi_i,
    const float* __restrict__ br_o, const float* __restrict__ bi_o,
    const float* __restrict__ br_c, const float* __restrict__ bi_c,
    short* __restrict__ Wp, float* __restrict__ bias) {
  int blk = blockIdx.x;
  int tid = threadIdx.x;

  if (blk < 520) {                        // ---- halo zero
    int t = blk * 256 + tid;              // 4160 px * 32
    int s   = t & 31;
    int pix = t >> 5;
    int b = pix / 260;
    int r = pix - b * 260;
    int yp, xp;
    if (r < 66)       { yp = 0;               xp = r; }
    else if (r < 132) { yp = 65;              xp = r - 66; }
    else { int r2 = r - 132; yp = 1 + (r2 >> 1); xp = (r2 & 1) * 65; }
    short8 z;
#pragma unroll
    for (int q = 0; q < 8; ++q) z[q] = 0;
    *(short8*)(Zp + (((b * 66 + yp) * 66 + xp) * 256 + s * 8)) = z;
    return;
  }

  if (blk < 520 + 4096) {                 // ---- pack Z, LDS-free
    int bid = blk - 520;
    int y      = bid & 63;
    int half   = (bid >> 6) & 1;
    int srcSel = (bid >> 7) & 1;
    int b      = bid >> 8;
    const float* src = srcSel ? hs : xs;
    int chBase  = half * 64;
    int cinBase = half * 128 + srcSel * 64;
    int seg8 = tid & 7, xg = tid >> 3;    // 8 cin-octets x 32 x-pairs
    int x0 = xg * 2;
    short8 v0, v1;
#pragma unroll
    for (int k = 0; k < 8; ++k) {
      float2v f = *(const float2v*)(src +
          (size_t)(b * 128 + chBase + seg8 * 8 + k) * 4096 + y * 64 + x0);
      v0[k] = f2bf(f[0]);
      v1[k] = f2bf(f[1]);
    }
    size_t outp = ((size_t)(b * 66 + y + 1) * 66 + x0 + 1) * 256 + cinBase + seg8 * 8;
    *(short8*)(Zp + outp)       = v0;
    *(short8*)(Zp + outp + 256) = v1;
    return;
  }

  {                                       // ---- pack W + bias
    int g = (blk - 4616) * 256 + tid;
    if (g >= 384 * 9 * 256) return;
    int cin = g & 255;
    int tap = (g >> 8) % 9;
    int n   = g / (256 * 9);
    int part = n >> 6, ch = n & 63;
    const float *Wr, *Wi;
    if (part < 2)      { Wr = Wr_i; Wi = Wi_i; }
    else if (part < 4) { Wr = Wr_o; Wi = Wi_o; }
    else               { Wr = Wr_c; Wi = Wi_c; }
    int im = part & 1;
    int ci = cin & 127;
    int second = cin >> 7;
    const float* src = im ? (second ? Wr : Wi) : (second ? Wi : Wr);
    float f = src[(ch * 128 + ci) * 9 + tap];
    if (!im && second) f = -f;
    Wp[(n * 9 + tap) * 256 + cin] = f2bf(f);
    if (g < 384) {
      int p2 = g >> 6, c2 = g & 63;
      const float* bs = (p2 == 0) ? br_i : (p2 == 1) ? bi_i : (p2 == 2) ? br_o
                      : (p2 == 3) ? bi_o : (p2 == 4) ? br_c : bi_c;
      bias[g] = bs[c2];
    }
  }
}

// ---------------------------------------------------------------- conv + fused epilogue
// A: 384 rows x 32 k; LDS slot (16B, 8 k) = (row>>1)*8 + ((2*kg+(row&7))&7).
// B: 4 rows x 66 cols x 32 k; per row 264 slots: interior (col 1..64) at
//    off = ((col-1)>>1)*8 + ((2*kg+((col-1)&7))&7) in [0,256); halo col0 at
//    256+kg, col65 at 260+kg (zeroed once, both buffers).
__device__ __forceinline__ void issueA(const short* __restrict__ Wp, int tapkc,
                                       short8* dst, int tid, int wv) {
#pragma unroll
  for (int it = 0; it < 3; ++it) {
    int idx = tid + it * 512;           // 0..1535 = LDS slot
    int rp  = idx >> 3;
    int q   = idx & 7;
    int row = rp * 2 + (q & 1);
    int kg  = ((q >> 1) - rp) & 3;
    gload16(Wp + ((size_t)row * 2304 + tapkc + kg * 8),
            (void*)(dst + (it * 512 + wv * 64)));
  }
}

__device__ __forceinline__ void issueBc(const short* __restrict__ Z, int zrow0,
                                        int kcn32, int tapc, short8* dst,
                                        int tid, int wv) {
  int s   = tapc * 512 + tid;           // 0..1023
  int r   = s >> 8;
  int off = s & 255;
  int cp  = off >> 3;
  int q   = off & 7;
  int col = 1 + cp * 2 + (q & 1);
  int kg  = ((q >> 1) - cp) & 3;
  int s0  = tapc * 512 + wv * 64;       // wave-uniform dest base
  gload16(Z + ((size_t)((zrow0 + r) * 66 + col) * 256 + kcn32 + kg * 8),
          (void*)(dst + ((s0 >> 8) * 264 + (s0 & 255))));
}

template<int DYN, int DXN>
__device__ __forceinline__ void readFrags(const short8* __restrict__ Ab,
                                          const short8* __restrict__ Bb0,
                                          short8 (&af)[6], short8 (&bf)[4],
                                          int aSlot, int wpx, int l15, int l4) {
  const short8* Bb = Bb0 + (wpx + DYN) * 264;
#pragma unroll
  for (int i = 0; i < 6; ++i) af[i] = Ab[aSlot + i * 64];
#pragma unroll
  for (int j = 0; j < 4; ++j) {
    int col = j * 16 + l15 + DXN;
    int cm  = col - 1;
    int s   = (cm >> 1) * 8 + ((2 * l4 + (cm & 7)) & 7);
    if (DXN == 0 && j == 0) { if (col == 0)  s = 256 + l4; }
    if (DXN == 2 && j == 3) { if (col == 65) s = 260 + l4; }
    bf[j] = Bb[s];
  }
}

__device__ __forceinline__ void mfma24(const short8 (&af)[6], const short8 (&bf)[4],
                                       floatx4 (&acc)[6][4]) {
  __builtin_amdgcn_s_setprio(1);
#pragma unroll
  for (int i = 0; i < 6; ++i)
#pragma unroll
    for (int j = 0; j < 4; ++j)
      acc[i][j] = __builtin_amdgcn_mfma_f32_16x16x32_bf16(af[i], bf[j], acc[i][j], 0, 0, 0);
  __builtin_amdgcn_s_setprio(0);
}

__device__ __forceinline__ float fsig(float v) { return 1.f / (1.f + __expf(-v)); }
__device__ __forceinline__ float ftanh(float v) {
  float e = __expf(2.f * v);
  return 1.f - 2.f / (e + 1.f);
}

__global__ __launch_bounds__(512, 2) void conv_fused(
    const short* __restrict__ Z, const short* __restrict__ Wp,
    const float* __restrict__ bias, const float* __restrict__ x,
    const float* __restrict__ c_prev, float* __restrict__ out) {
  __shared__ short8 As[2][1536];   // 49,152 B (epilogue Ex reuses As[0])
  __shared__ short8 Bs[2][1056];   // 33,792 B

  const int tid = threadIdx.x;
  const int wv = tid >> 6, lane = tid & 63;
  const int l15 = lane & 15, l4 = lane >> 4;
  const int wc4 = wv & 3;          // ch-quarter: rows wc4*96 .. +95
  const int wpx = wv >> 2;         // px y-row 0/1
  const int pb = blockIdx.x;
  const int b  = pb >> 5;          // batch
  const int y0 = (pb & 31) * 2;    // first output row
  const int zrow0 = b * 66 + y0;   // padded rows y0..y0+3 = inputs y0-1..y0+2

  // A frag slot: row = wc4*96 + i*16 + l15, kg = l4 (stride i: 8 pairs = 64 slots)
  const int aSlot = (wc4 * 48 + (l15 >> 1)) * 8 + ((2 * l4 + (l15 & 7)) & 7);

  floatx4 acc[6][4];
#pragma unroll
  for (int i = 0; i < 6; ++i)
#pragma unroll
    for (int j = 0; j < 4; ++j)
#pragma unroll
      for (int r = 0; r < 4; ++r) acc[i][j][r] = 0.f;

  short8 afA[6], bfA[4], afB[6], bfB[4];

  // -- prologue: zero halo slots (both B bufs); stage A[0], B[kc0], A[1].
  if (tid < 64) {
    int buf = tid >> 5, w5 = tid & 31;
    int r = w5 >> 3, h = (w5 >> 2) & 1, kg = w5 & 3;
    short8 z;
#pragma unroll
    for (int q = 0; q < 8; ++q) z[q] = 0;
    Bs[buf][r * 264 + 256 + h * 4 + kg] = z;
  }
  issueA(Wp, 0, &As[0][0], tid, wv);            // A[0] = (kc0, tap0)
  issueBc(Z, zrow0, 0, 0, &Bs[0][0], tid, wv);  // B[kc0] chunk 0
  issueBc(Z, zrow0, 0, 1, &Bs[0][0], tid, wv);  // B[kc0] chunk 1
  issueA(Wp, 256, &As[1][0], tid, wv);          // A[1] = (kc0, tap1)
  __builtin_amdgcn_sched_barrier(0);
  asm volatile("s_waitcnt vmcnt(3) lgkmcnt(0)" ::: "memory");  // A0,B0 landed
  __builtin_amdgcn_sched_barrier(0);
  __builtin_amdgcn_s_barrier();
  __builtin_amdgcn_sched_barrier(0);
  readFrags<0, 0>(&As[0][0], &Bs[0][0], afA, bfA, aSlot, wpx, l15, l4);

  // STEP s = kc*9 + TAP. PS = (TAP+PE)&1, PE = kc&1.
#define STEP(TAP, PE, KCV)                                                     \
  {                                                                            \
    constexpr int PS   = ((TAP) + (PE)) & 1;                                   \
    constexpr int TAPN = ((TAP) + 1) % 9;                                      \
    constexpr int PBN  = ((TAP) == 8) ? ((PE) ^ 1) : (PE);                     \
    if constexpr ((TAP) == 1 || (TAP) == 2)                                    \
      asm volatile("s_waitcnt vmcnt(1) lgkmcnt(0)" ::: "memory");              \
    else                                                                       \
      asm volatile("s_waitcnt vmcnt(0) lgkmcnt(0)" ::: "memory");              \
    __builtin_amdgcn_sched_barrier(0);                                         \
    __builtin_amdgcn_s_barrier();                                              \
    __builtin_amdgcn_sched_barrier(0);                                         \
    if constexpr (PS == 0)                                                     \
      readFrags<TAPN / 3, TAPN % 3>(&As[1][0], &Bs[PBN][0], afB, bfB,          \
                                    aSlot, wpx, l15, l4);                      \
    else                                                                       \
      readFrags<TAPN / 3, TAPN % 3>(&As[0][0], &Bs[PBN][0], afA, bfA,          \
                                    aSlot, wpx, l15, l4);                      \
    { const int kc2 = ((TAP) <= 6) ? (KCV) : (KCV) + 1;                        \
      issueA(Wp, (((TAP) + 2) % 9) * 256 + kc2 * 32, &As[PS][0], tid, wv); }   \
    if constexpr ((TAP) == 0 || (TAP) == 1)                                    \
      issueBc(Z, zrow0, ((KCV) + 1) * 32, (TAP), &Bs[(PE) ^ 1][0], tid, wv);   \
    if constexpr (PS == 0) mfma24(afA, bfA, acc);                              \
    else                   mfma24(afB, bfB, acc);                              \
  }

  for (int kq = 0; kq < 4; ++kq) {
    const int kE = kq * 2, kO = kE + 1;
    STEP(0, 0, kE) STEP(1, 0, kE) STEP(2, 0, kE) STEP(3, 0, kE) STEP(4, 0, kE)
    STEP(5, 0, kE) STEP(6, 0, kE) STEP(7, 0, kE) STEP(8, 0, kE)
    STEP(0, 1, kO) STEP(1, 1, kO) STEP(2, 1, kO) STEP(3, 1, kO) STEP(4, 1, kO)
    STEP(5, 1, kO) STEP(6, 1, kO) STEP(7, 1, kO) STEP(8, 1, kO)
  }
#undef STEP

  // -- fused epilogue: drain junk DMAs; 2 px-rows x 2 c-halves, Ex stride 68.
  asm volatile("s_waitcnt vmcnt(0) lgkmcnt(0)" ::: "memory");
  __syncthreads();
  short* Ex = (short*)&As[0][0];   // 192 rows x 68 shorts = 26,112 B
#pragma unroll
  for (int l = 0; l < 2; ++l) {
#pragma unroll
    for (int hf = 0; hf < 2; ++hf) {
      if (wpx == l) {
#pragma unroll
        for (int i = 0; i < 6; ++i) {
          int chb = wc4 * 96 + i * 16;
          if (((chb >> 5) & 1) == hf) {
#pragma unroll
            for (int j = 0; j < 4; ++j)
#pragma unroll
              for (int rr = 0; rr < 4; ++rr) {
                int ch = chb + l4 * 4 + rr;
                int row = (ch >> 6) * 32 + (ch & 31);
                Ex[row * 68 + j * 16 + l15] = f2bf(acc[i][j][rr] + bias[ch]);
              }
          }
        }
      }
      __syncthreads();
      {
        int xg = tid & 63, cg = tid >> 6;   // 8 groups x 4 c
#pragma unroll
        for (int k = 0; k < 4; ++k) {
          int c5 = cg * 4 + k;              // 0..31
          int c  = hf * 32 + c5;
          float yri = bf2f(Ex[(0 * 32 + c5) * 68 + xg]);
          float yii = bf2f(Ex[(1 * 32 + c5) * 68 + xg]);
          float yro = bf2f(Ex[(2 * 32 + c5) * 68 + xg]);
          float yio = bf2f(Ex[(3 * 32 + c5) * 68 + xg]);
          float yrc = bf2f(Ex[(4 * 32 + c5) * 68 + xg]);
          float yic = bf2f(Ex[(5 * 32 + c5) * 68 + xg]);
          float i_r = fsig(yri), i_i = fsig(yii);
          float o_r = fsig(yro), o_i = fsig(yio);
          float ct_r = ftanh(yrc), ct_i = ftanh(yic);
          int base = (b * 128 + c) * 4096 + (y0 + l) * 64 + xg;
          float xr = x[base];
          float xi = x[base + 64 * 4096];
          float cr = c_prev[base];
          float ci = c_prev[base + 64 * 4096];
          float cnr = xr * cr - xi * ci + i_r * ct_r - i_i * ct_i;
          float cni = xr * ci + xi * cr + i_r * ct_i + i_i * ct_r;
          float tr = ftanh(cnr), ti = ftanh(cni);
          out[base]                     = o_r * tr - o_i * ti;
          out[base + 64 * 4096]         = o_r * ti + o_i * tr;
          out[HSIZE + base]             = cnr;
          out[HSIZE + base + 64 * 4096] = cni;
        }
      }
      __syncthreads();
    }
  }
}

// ---------------------------------------------------------------- launch
extern "C" void kernel_launch(void* const* d_in, const int* in_sizes, int n_in,
                              void* d_out, int out_size, void* d_ws, size_t ws_size,
                              hipStream_t stream) {
  // inputs: 0 x, 1 h_prev, 2 c_prev,
  //         3 Wr_i, 4 Wi_i, 5 br_i, 6 bi_i,  7..10 f-gate (unused),
  //        11 Wr_o,12 Wi_o,13 br_o,14 bi_o, 15 Wr_c,16 Wi_c,17 br_c,18 bi_c
  char* ws = (char*)d_ws;
  short* Zp   = (short*)ws;                          // 35,684,352 B
  short* Wp   = (short*)(ws + 35684352);             //  1,769,472 B
  float* bias = (float*)(ws + 37453824);             //      1,536 B

  prep_kernel<<<8072, 256, 0, stream>>>(
      (const float*)d_in[0], (const float*)d_in[1], Zp,
      (const float*)d_in[3], (const float*)d_in[4],
      (const float*)d_in[11], (const float*)d_in[12],
      (const float*)d_in[15], (const float*)d_in[16],
      (const float*)d_in[5], (const float*)d_in[6],
      (const float*)d_in[13], (const float*)d_in[14],
      (const float*)d_in[17], (const float*)d_in[18],
      Wp, bias);
  conv_fused<<<512, 512, 0, stream>>>(
      Zp, Wp, bias, (const float*)d_in[0], (const float*)d_in[2],
      (float*)d_out);
}